// Round 1
// baseline (207.327 us; speedup 1.0000x reference)
//
#include <hip/hip_runtime.h>

#define BINS      4096
#define NIMG      64
#define IMG_ELEMS (512*512)
#define BPI       8                 // histogram blocks per image
#define THREADS   512
#define CHUNK     (IMG_ELEMS / BPI) // 32768 elems per block
#define EMAX      6.5f

// Region layout (one region = one sub-histogram):
//   u32 cp[BINS] | u32 cn[BINS] | f32 sp[BINS] | f32 sn[BINS]   (64 KB)
// privateMode: region per block (NIMG*BPI regions, plain stores)
// atomicMode : region per image (NIMG regions, atomicAdd, pre-zeroed)

__global__ __launch_bounds__(THREADS, 4)
void lovasz_hist(const float* __restrict__ pred, const float* __restrict__ tgt,
                 unsigned* __restrict__ regions, unsigned* __restrict__ Pcnt,
                 int privateMode) {
    __shared__ unsigned cnt[BINS];   // packed: pos<<16 | neg (block-local, <=32768 each)
    __shared__ float    sps[BINS];
    __shared__ float    sns[BINS];
    const int bx  = blockIdx.x;
    const int img = bx / BPI, sub = bx % BPI;
    const int tid = threadIdx.x;

    for (int i = tid; i < BINS; i += THREADS) { cnt[i] = 0u; sps[i] = 0.f; sns[i] = 0.f; }
    __syncthreads();

    const size_t base = (size_t)img * IMG_ELEMS + (size_t)sub * CHUNK;
    const float4* p4 = (const float4*)(pred + base);
    const float4* t4 = (const float4*)(tgt + base);
    const float scale = (float)BINS / EMAX;

    unsigned posc = 0;
    for (int i = tid; i < CHUNK/4; i += THREADS) {
        float4 p = p4[i]; float4 t = t4[i];
        float pa[4] = {p.x, p.y, p.z, p.w};
        float ta[4] = {t.x, t.y, t.z, t.w};
        #pragma unroll
        for (int k = 0; k < 4; ++k) {
            bool pos = ta[k] > 0.5f;
            posc += pos ? 1u : 0u;                    // P counts ALL positives
            float e = 1.f - pa[k] * (pos ? 1.f : -1.f);
            if (e > 0.f) {                            // relu gate: e<=0 contributes 0
                int b = (int)(e * scale); if (b > BINS-1) b = BINS-1;
                atomicAdd(&cnt[b], pos ? 0x10000u : 1u);
                atomicAdd(pos ? &sps[b] : &sns[b], e);
            }
        }
    }
    // wave-reduce positive count, one atomic per wave
    for (int off = 32; off; off >>= 1) posc += __shfl_down(posc, off, 64);
    if ((tid & 63) == 0) atomicAdd(&Pcnt[img], posc);
    __syncthreads();

    unsigned* reg  = regions + (size_t)(privateMode ? bx : img) * (4*BINS);
    float*    regf = (float*)reg;
    if (privateMode) {
        for (int i = tid; i < BINS; i += THREADS) {
            unsigned c = cnt[i];
            reg[i]            = c >> 16;
            reg[BINS + i]     = c & 0xFFFFu;
            regf[2*BINS + i]  = sps[i];
            regf[3*BINS + i]  = sns[i];
        }
    } else {
        for (int i = tid; i < BINS; i += THREADS) {
            unsigned c = cnt[i];
            if (c) {
                atomicAdd(&reg[i],        c >> 16);
                atomicAdd(&reg[BINS + i], c & 0xFFFFu);
            }
            float a = sps[i], b = sns[i];
            if (a != 0.f) atomicAdd(&regf[2*BINS + i], a);
            if (b != 0.f) atomicAdd(&regf[3*BINS + i], b);
        }
    }
}

// One block per image: aggregate sub-histograms, suffix-scan counts (descending e),
// evaluate closed-form per-bin Lovasz terms in fp64.
__global__ __launch_bounds__(256)
void lovasz_loss(const unsigned* __restrict__ regions, const unsigned* __restrict__ Pcnt,
                 float* __restrict__ out, int nsub) {
    __shared__ unsigned cp[BINS];
    __shared__ unsigned cn[BINS];
    __shared__ float    sp[BINS];
    __shared__ float    sn[BINS];
    __shared__ unsigned long long scan[256];
    __shared__ double   red[256];
    const int img = blockIdx.x, tid = threadIdx.x;

    for (int i = tid; i < BINS; i += 256) { cp[i]=0u; cn[i]=0u; sp[i]=0.f; sn[i]=0.f; }
    __syncthreads();
    for (int s = 0; s < nsub; ++s) {
        const unsigned* h  = regions + (size_t)(img*nsub + s) * (4*BINS);
        const float*    hf = (const float*)h;
        for (int i = tid; i < BINS; i += 256) {
            cp[i] += h[i];
            cn[i] += h[BINS + i];
            sp[i] += hf[2*BINS + i];
            sn[i] += hf[3*BINS + i];
        }
    }
    __syncthreads();

    // per-thread totals over its 16 bins, packed (pos<<32 | neg)
    const int b0 = tid * 16;
    unsigned aT = 0, cT = 0;
    for (int j = 0; j < 16; ++j) { aT += cp[b0+j]; cT += cn[b0+j]; }
    scan[tid] = ((unsigned long long)aT << 32) | (unsigned long long)cT;
    __syncthreads();
    // inclusive suffix scan over threads (Hillis-Steele)
    for (int off = 1; off < 256; off <<= 1) {
        unsigned long long v = (tid + off < 256) ? scan[tid + off] : 0ull;
        __syncthreads();
        scan[tid] += v;
        __syncthreads();
    }
    unsigned long long above = (tid < 255) ? scan[tid + 1] : 0ull;

    const double P = (double)Pcnt[img];
    double p_above = (double)(unsigned)(above >> 32);
    double n_above = (double)(unsigned)(above & 0xFFFFFFFFull);
    double acc = 0.0;
    // walk own bins from highest e to lowest
    for (int j = 15; j >= 0; --j) {
        int b = b0 + j;
        double a = (double)cp[b], c = (double)cn[b];
        double Pn = P + n_above;
        // positives first (each weight 1/(P+n_above)), negatives with averaged ranks
        acc += (double)sp[b] / Pn
             + (double)sn[b] * (P - p_above - a) / (Pn * (Pn + c));
        p_above += a; n_above += c;
    }
    red[tid] = acc;
    __syncthreads();
    for (int off = 128; off; off >>= 1) {
        if (tid < off) red[tid] += red[tid + off];
        __syncthreads();
    }
    if (tid == 0) atomicAdd(out, (float)(red[0] / (double)NIMG));
}

extern "C" void kernel_launch(void* const* d_in, const int* in_sizes, int n_in,
                              void* d_out, int out_size, void* d_ws, size_t ws_size,
                              hipStream_t stream) {
    const float* pred = (const float*)d_in[0];
    const float* tgt  = (const float*)d_in[1];

    const size_t regionBytes = (size_t)4 * BINS * 4; // 64 KB
    const size_t privNeed = (size_t)NIMG * BPI * regionBytes + 256;
    int privateMode = (ws_size >= privNeed) ? 1 : 0;
    int nregions    = privateMode ? NIMG * BPI : NIMG;

    unsigned* regions = (unsigned*)d_ws;
    unsigned* Pcnt    = (unsigned*)((char*)d_ws + (size_t)nregions * regionBytes);

    if (!privateMode) {
        // atomic mode: regions must start zeroed (ws is poisoned 0xAA)
        hipMemsetAsync(regions, 0, (size_t)nregions * regionBytes, stream);
    }
    hipMemsetAsync(Pcnt, 0, NIMG * sizeof(unsigned), stream);
    hipMemsetAsync(d_out, 0, sizeof(float), stream);

    lovasz_hist<<<NIMG * BPI, THREADS, 0, stream>>>(pred, tgt, regions, Pcnt, privateMode);
    lovasz_loss<<<NIMG, 256, 0, stream>>>(regions, Pcnt, (float*)d_out,
                                          privateMode ? BPI : 1);
}